// Round 1
// baseline (386.213 us; speedup 1.0000x reference)
//
#include <hip/hip_runtime.h>
#include <math.h>

// Problem constants
constexpr int CB = 8;      // batch
constexpr int CS = 1024;   // seq
constexpr int CD = 512;    // model dim
constexpr int CH = 8;      // heads
constexpr int CHD = 64;    // head dim
constexpr int CDFF = 2048; // ffn dim
constexpr int NROW = CB * CS;

typedef unsigned short u16;
typedef unsigned int u32;
typedef __attribute__((ext_vector_type(8))) short short8;
typedef __attribute__((ext_vector_type(8))) unsigned short ushort8v;
typedef __attribute__((ext_vector_type(4))) float floatx4;

__device__ inline u16 f2bf(float f) {
    union { float f; unsigned u; } v; v.f = f;
    unsigned u = v.u + 0x7FFFu + ((v.u >> 16) & 1u);  // RNE
    return (u16)(u >> 16);
}
__device__ inline float bf2f(u16 h) {
    union { unsigned u; float f; } v; v.u = ((unsigned)h) << 16;
    return v.f;
}

// async global->LDS, 16B per lane; LDS dest is wave-uniform base + lane*16
__device__ inline void gload16(const u16* g, u16* l) {
    __builtin_amdgcn_global_load_lds(
        (const __attribute__((address_space(1))) u32*)g,
        (__attribute__((address_space(3))) u32*)l, 16, 0, 0);
}

// ---------------------------------------------------------------------------
// LayerNorm (+ optional embedding add). One block per row, 256 threads.
// ---------------------------------------------------------------------------
__global__ __launch_bounds__(256) void ln_kernel(
    const float* __restrict__ x, const int* __restrict__ ids,
    const float* __restrict__ emb,
    const float* __restrict__ g, const float* __restrict__ beta,
    float* __restrict__ xr_out, u16* __restrict__ xn_out)
{
    __shared__ float red1[4], red2[4];
    __shared__ float mu_s, ri_s;
    int row = blockIdx.x;
    int tid = threadIdx.x;
    int d0 = tid * 2;
    const float* xrow = x + (size_t)row * CD;
    float2 xv = *(const float2*)(xrow + d0);
    float v0 = xv.x, v1 = xv.y;
    if (emb) {
        int id = ids[row];
        float2 ev = *(const float2*)(emb + (size_t)id * CD + d0);
        v0 += ev.x; v1 += ev.y;
    }
    float s1 = v0 + v1;
    float s2 = v0 * v0 + v1 * v1;
    for (int off = 32; off > 0; off >>= 1) {
        s1 += __shfl_down(s1, off, 64);
        s2 += __shfl_down(s2, off, 64);
    }
    int wave = tid >> 6;
    if ((tid & 63) == 0) { red1[wave] = s1; red2[wave] = s2; }
    __syncthreads();
    if (tid == 0) {
        float t1 = red1[0] + red1[1] + red1[2] + red1[3];
        float t2 = red2[0] + red2[1] + red2[2] + red2[3];
        float mu = t1 / CD;
        float var = t2 / CD - mu * mu;
        mu_s = mu;
        ri_s = rsqrtf(var + 1e-5f);
    }
    __syncthreads();
    float mu = mu_s, ri = ri_s;
    if (xr_out) {
        float2 o; o.x = v0; o.y = v1;
        *(float2*)(xr_out + (size_t)row * CD + d0) = o;
    }
    float2 gv = *(const float2*)(g + d0);
    float2 bv = *(const float2*)(beta + d0);
    float n0 = (v0 - mu) * ri * gv.x + bv.x;
    float n1 = (v1 - mu) * ri * gv.y + bv.y;
    u32 pk = (u32)f2bf(n0) | ((u32)f2bf(n1) << 16);
    *(u32*)(xn_out + (size_t)row * CD + d0) = pk;
}

// ---------------------------------------------------------------------------
// fp32 -> bf16 elementwise convert (weights), 8 elems/thread
// ---------------------------------------------------------------------------
__global__ __launch_bounds__(256) void conv_kernel(
    const float* __restrict__ src, u16* __restrict__ dst)
{
    size_t i = ((size_t)blockIdx.x * 256 + threadIdx.x) * 8;
    float4 a = *(const float4*)(src + i);
    float4 b = *(const float4*)(src + i + 4);
    ushort8v o;
    o[0] = f2bf(a.x); o[1] = f2bf(a.y); o[2] = f2bf(a.z); o[3] = f2bf(a.w);
    o[4] = f2bf(b.x); o[5] = f2bf(b.y); o[6] = f2bf(b.z); o[7] = f2bf(b.w);
    *(ushort8v*)(dst + i) = o;
}

// ---------------------------------------------------------------------------
// bf16 MFMA GEMM, 128x128 tile (m97 recipe): C = act(A @ W^T + bias)(+res)
// ---------------------------------------------------------------------------
template <int ACT, int RES, int OUTBF>
__global__ __launch_bounds__(256) void gemm_mfma(
    const u16* __restrict__ A, const u16* __restrict__ W,
    const float* __restrict__ bias, const float* __restrict__ res,
    void* __restrict__ Cout, int M, int N, int K)
{
    __shared__ u16 As[128 * 32];
    __shared__ u16 Bs[128 * 32];
    int t = threadIdx.x;
    int lane = t & 63;
    int w = t >> 6;
    int m0 = blockIdx.x * 128;
    int n0 = blockIdx.y * 128;
    int col = lane & 15;
    int quad = lane >> 4;
    int wm = w & 1, wn = w >> 1;

    const u16* ag = A + (size_t)(m0 + (t >> 2)) * K + (t & 3) * 8;
    const u16* ag2 = ag + (size_t)64 * K;
    const u16* bg = W + (size_t)(n0 + (t >> 2)) * K + (t & 3) * 8;
    const u16* bg2 = bg + (size_t)64 * K;
    u16* la = As + w * 512;
    u16* lb = Bs + w * 512;

    floatx4 acc[4][4];
#pragma unroll
    for (int i = 0; i < 4; i++)
#pragma unroll
        for (int j = 0; j < 4; j++) acc[i][j] = (floatx4){0.f, 0.f, 0.f, 0.f};

    for (int kt = 0; kt < K; kt += 32) {
        gload16(ag + kt, la);
        gload16(ag2 + kt, la + 2048);
        gload16(bg + kt, lb);
        gload16(bg2 + kt, lb + 2048);
        __syncthreads();
        short8 af[4], bf[4];
#pragma unroll
        for (int mi = 0; mi < 4; mi++)
            af[mi] = *(const short8*)&As[(wm * 64 + mi * 16 + col) * 32 + quad * 8];
#pragma unroll
        for (int ni = 0; ni < 4; ni++)
            bf[ni] = *(const short8*)&Bs[(wn * 64 + ni * 16 + col) * 32 + quad * 8];
#pragma unroll
        for (int mi = 0; mi < 4; mi++)
#pragma unroll
            for (int ni = 0; ni < 4; ni++)
                acc[mi][ni] = __builtin_amdgcn_mfma_f32_16x16x32_bf16(
                    af[mi], bf[ni], acc[mi][ni], 0, 0, 0);
        __syncthreads();
    }

#pragma unroll
    for (int mi = 0; mi < 4; mi++)
#pragma unroll
        for (int ni = 0; ni < 4; ni++) {
            int c = n0 + wn * 64 + ni * 16 + col;
            float bv = bias[c];
#pragma unroll
            for (int r = 0; r < 4; r++) {
                int m = m0 + wm * 64 + mi * 16 + quad * 4 + r;
                float v = acc[mi][ni][r] + bv;
                if (ACT == 1) v = 0.5f * v * (1.0f + erff(v * 0.70710678118654752f));
                if (RES) v += res[(size_t)m * N + c];
                if (OUTBF) ((u16*)Cout)[(size_t)m * N + c] = f2bf(v);
                else       ((float*)Cout)[(size_t)m * N + c] = v;
            }
        }
}

// ---------------------------------------------------------------------------
// bf16 MFMA GEMM, 64x128 tile — for N=512 layers (512 blocks -> 2/CU)
// ---------------------------------------------------------------------------
template <int ACT, int RES, int OUTBF>
__global__ __launch_bounds__(256) void gemm_mfma64(
    const u16* __restrict__ A, const u16* __restrict__ W,
    const float* __restrict__ bias, const float* __restrict__ res,
    void* __restrict__ Cout, int M, int N, int K)
{
    __shared__ u16 As[64 * 32];
    __shared__ u16 Bs[128 * 32];
    int t = threadIdx.x;
    int lane = t & 63;
    int w = t >> 6;
    int m0 = blockIdx.x * 64;
    int n0 = blockIdx.y * 128;
    int col = lane & 15;
    int quad = lane >> 4;

    const u16* ag = A + (size_t)(m0 + (t >> 2)) * K + (t & 3) * 8;
    const u16* bg = W + (size_t)(n0 + (t >> 2)) * K + (t & 3) * 8;
    const u16* bg2 = bg + (size_t)64 * K;
    u16* la = As + w * 512;
    u16* lb = Bs + w * 512;

    floatx4 acc[4][2];
#pragma unroll
    for (int i = 0; i < 4; i++)
#pragma unroll
        for (int j = 0; j < 2; j++) acc[i][j] = (floatx4){0.f, 0.f, 0.f, 0.f};

    for (int kt = 0; kt < K; kt += 32) {
        gload16(ag + kt, la);
        gload16(bg + kt, lb);
        gload16(bg2 + kt, lb + 2048);
        __syncthreads();
        short8 af[4], bf[2];
#pragma unroll
        for (int mi = 0; mi < 4; mi++)
            af[mi] = *(const short8*)&As[(mi * 16 + col) * 32 + quad * 8];
#pragma unroll
        for (int ni = 0; ni < 2; ni++)
            bf[ni] = *(const short8*)&Bs[(w * 32 + ni * 16 + col) * 32 + quad * 8];
#pragma unroll
        for (int mi = 0; mi < 4; mi++)
#pragma unroll
            for (int ni = 0; ni < 2; ni++)
                acc[mi][ni] = __builtin_amdgcn_mfma_f32_16x16x32_bf16(
                    af[mi], bf[ni], acc[mi][ni], 0, 0, 0);
        __syncthreads();
    }

#pragma unroll
    for (int mi = 0; mi < 4; mi++)
#pragma unroll
        for (int ni = 0; ni < 2; ni++) {
            int c = n0 + w * 32 + ni * 16 + col;
            float bv = bias[c];
#pragma unroll
            for (int r = 0; r < 4; r++) {
                int m = m0 + mi * 16 + quad * 4 + r;
                float v = acc[mi][ni][r] + bv;
                if (ACT == 1) v = 0.5f * v * (1.0f + erff(v * 0.70710678118654752f));
                if (RES) v += res[(size_t)m * N + c];
                if (OUTBF) ((u16*)Cout)[(size_t)m * N + c] = f2bf(v);
                else       ((float*)Cout)[(size_t)m * N + c] = v;
            }
        }
}

// ---------------------------------------------------------------------------
// Q/K repack: qkv [B,S,1536] col-slice -> [b][h][s][64] contiguous (128B rows)
// makes attn QK loads fully coalesced (wave reads contiguous 2KB)
// ---------------------------------------------------------------------------
__global__ __launch_bounds__(256) void kpack_kernel(
    const u16* __restrict__ qkvb, u16* __restrict__ dst, int coff)
{
    size_t i = ((size_t)blockIdx.x * 256 + threadIdx.x) * 8;  // output index
    int d = (int)(i & 63);
    int s = (int)((i >> 6) & (CS - 1));
    int h = (int)((i >> 16) & (CH - 1));
    int b = (int)(i >> 19);
    const u16* src = qkvb + (size_t)(b * CS + s) * 1536 + coff + h * CHD + d;
    *(ushort8v*)(dst + i) = *(const ushort8v*)src;
}

// ---------------------------------------------------------------------------
// V repack: qkv cols 1024.. -> [b][h][S/64][64d][64k] 4KB tiles.
// PV B-fragment pair then reads a contiguous 2KB slice per wave.
// ---------------------------------------------------------------------------
__global__ __launch_bounds__(256) void vpack_kernel(
    const u16* __restrict__ qkvb, u16* __restrict__ vp)
{
    __shared__ u16 tile[64][72];
    int b = blockIdx.x >> 4;
    int s0 = (blockIdx.x & 15) * 64;
    int h = blockIdx.y;
    int t = threadIdx.x;
    int r = t >> 2;          // load phase: s-row 0..63 / store phase: d-row 0..63
    int c0 = (t & 3) * 16;   // load: d chunk / store: key chunk
    const u16* src = qkvb + (size_t)(b * CS + s0 + r) * 1536 + 2 * CD + h * CHD + c0;
    *(ushort8v*)&tile[r][c0] = *(const ushort8v*)src;
    *(ushort8v*)&tile[r][c0 + 8] = *(const ushort8v*)(src + 8);
    __syncthreads();
    u16* dst = vp + (((size_t)(b * CH + h) * 16 + (s0 >> 6)) << 12) + r * 64 + c0;
    ushort8v lo, hi;
#pragma unroll
    for (int j = 0; j < 8; j++) { lo[j] = tile[c0 + j][r]; hi[j] = tile[c0 + 8 + j][r]; }
    *(ushort8v*)dst = lo;
    *(ushort8v*)(dst + 8) = hi;
}

// ---------------------------------------------------------------------------
// MFMA attention v8. Same decomposition as v7 (block = (b, 16 q rows), 512
// threads / 8 waves, loops 8 heads, S/rs parity double-buffer, 2 barriers per
// head) but all Q/K/V global loads are now COALESCED (packed layouts: each
// wave load-pair covers a contiguous 2KB block instead of 16 scattered
// cache lines) and K/V fragments are 1-deep register-double-buffered so the
// next tile's loads issue before the current tile's MFMA+exp.
// ---------------------------------------------------------------------------
__global__ __launch_bounds__(512, 4) void attn_mfma_kernel(
    const u16* __restrict__ qp, const u16* __restrict__ kp,
    const u16* __restrict__ vp,
    u16* __restrict__ ctx, float* __restrict__ aw_out)
{
    __shared__ u16 S[2][16][1032];
    __shared__ float rs[2][8][16];
    __shared__ float Oex[4][64][4];

    int tid = threadIdx.x;
    int lane = tid & 63;
    int w = tid >> 6;          // wave 0..7
    int b = blockIdx.x >> 6;
    int q0 = (blockIdx.x & 63) * 16;
    int col = lane & 15;
    int quad = lane >> 4;
    int qo = tid & 15;         // aw q ownership
    int kc = tid >> 4;         // aw key-chunk ownership 0..31
    int dsub = w & 3;          // PV d-subtile
    int khalf = w >> 2;        // PV key half

    float aw[32];
#pragma unroll
    for (int i = 0; i < 32; i++) aw[i] = 0.f;

    for (int h = 0; h < CH; h++) {
        int par = h & 1;
        // Q A-fragments (two d-halves), packed layout: coalesced
        const u16* qrow = qp + ((size_t)(b * CH + h) * CS + q0 + col) * CHD + quad * 8;
        short8 qa0 = *(const short8*)qrow;
        short8 qa1 = *(const short8*)(qrow + 32);

        // ---- QK: e = exp(s/8) -> S[par], partial rowsums ----
        // packed K: row (key) is 128B; wave covers contiguous 2KB per pair
        const u16* kbase = kp + ((size_t)(b * CH + h) * CS + w * 128 + col) * CHD + quad * 8;
        short8 kb0[2], kb1[2];
        kb0[0] = *(const short8*)kbase;
        kb1[0] = *(const short8*)(kbase + 32);
        float esum[4] = {0.f, 0.f, 0.f, 0.f};
#pragma unroll
        for (int st = 0; st < 8; st++) {
            if (st < 7) {   // prefetch next key-tile while computing this one
                const u16* nk = kbase + (size_t)(st + 1) * (16 * CHD);
                kb0[(st + 1) & 1] = *(const short8*)nk;
                kb1[(st + 1) & 1] = *(const short8*)(nk + 32);
            }
            int key0 = w * 128 + st * 16;
            floatx4 c = {0.f, 0.f, 0.f, 0.f};
            c = __builtin_amdgcn_mfma_f32_16x16x32_bf16(qa0, kb0[st & 1], c, 0, 0, 0);
            c = __builtin_amdgcn_mfma_f32_16x16x32_bf16(qa1, kb1[st & 1], c, 0, 0, 0);
#pragma unroll
            for (int r = 0; r < 4; r++) {
                float e = __expf(c[r] * 0.125f);
                esum[r] += e;
                union { float f; u32 u; } pu; pu.f = e;
                S[par][quad * 4 + r][key0 + col] = (u16)(pu.u >> 16);  // bf16 trunc
            }
        }
#pragma unroll
        for (int r = 0; r < 4; r++) {
            esum[r] += __shfl_xor(esum[r], 1, 64);
            esum[r] += __shfl_xor(esum[r], 2, 64);
            esum[r] += __shfl_xor(esum[r], 4, 64);
            esum[r] += __shfl_xor(esum[r], 8, 64);
        }
        if (col == 0) {
#pragma unroll
            for (int r = 0; r < 4; r++) rs[par][w][quad * 4 + r] = esum[r];
        }
        __syncthreads();   // barrier A: S[par], rs[par] complete

        // ---- aw accumulation: all 512 threads, 32 cells each ----
        {
            float L = 0.f;
#pragma unroll
            for (int j = 0; j < 8; j++) L += rs[par][j][qo];
            float liq = 0.125f / L;
#pragma unroll
            for (int i = 0; i < 8; i++) {
                int key = kc * 4 + i * 128;
                ushort4 sv = *(const ushort4*)&S[par][qo][key];
                aw[i * 4 + 0] += bf2f(sv.x) * liq;
                aw[i * 4 + 1] += bf2f(sv.y) * liq;
                aw[i * 4 + 2] += bf2f(sv.z) * liq;
                aw[i * 4 + 3] += bf2f(sv.w) * liq;
            }
        }

        // ---- PV: wave w -> d-subtile dsub, keys [khalf*512, +512) ----
        // packed V tiles [64d][64k]: wave load-pair covers contiguous 2KB
        floatx4 oc0 = {0.f, 0.f, 0.f, 0.f};
        floatx4 oc1 = {0.f, 0.f, 0.f, 0.f};
        const u16* vtile = vp + (((size_t)(b * CH + h) * 16 + khalf * 8) << 12)
                           + (dsub * 16 + col) * 64 + quad * 8;
        short8 vb0[2], vb1[2];
        vb0[0] = *(const short8*)vtile;
        vb1[0] = *(const short8*)(vtile + 32);
#pragma unroll
        for (int kt = 0; kt < 8; kt++) {
            if (kt < 7) {   // prefetch next V tile
                const u16* nv = vtile + (size_t)(kt + 1) * 4096;
                vb0[(kt + 1) & 1] = *(const short8*)nv;
                vb1[(kt + 1) & 1] = *(const short8*)(nv + 32);
            }
            int key0 = khalf * 512 + kt * 64;
            short8 pa0 = *(const short8*)&S[par][col][key0 + quad * 8];
            oc0 = __builtin_amdgcn_mfma_f32_16x16x32_bf16(pa0, vb0[kt & 1], oc0, 0, 0, 0);
            short8 pa1 = *(const short8*)&S[par][col][key0 + 32 + quad * 8];
            oc1 = __builtin_amdgcn_mfma_f32_16x16x32_bf16(pa1, vb1[kt & 1], oc1, 0, 0, 0);
        }
        if (w >= 4) {
            Oex[dsub][lane][0] = oc0[0] + oc1[0];
            Oex[dsub][lane][1] = oc0[1] + oc1[1];
            Oex[dsub][lane][2] = oc0[2] + oc1[2];
            Oex[dsub][lane][3] = oc0[3] + oc1[3];
        }
        __syncthreads();   // barrier B: Oex complete
        if (w < 4) {
            float li[4];
#pragma unroll
            for (int r = 0; r < 4; r++) {
                int row = quad * 4 + r;
                float L = 0.f;
#pragma unroll
                for (int j = 0; j < 8; j++) L += rs[par][j][row];
                li[r] = 1.0f / L;
            }
            float4 op = *(const float4*)&Oex[dsub][lane][0];
            float po[4] = {op.x, op.y, op.z, op.w};
            u16* cb = ctx + ((size_t)(b * CS) + q0) * CD + h * CHD + dsub * 16 + col;
#pragma unroll
            for (int r = 0; r < 4; r++)
                cb[(size_t)(quad * 4 + r) * CD] = f2bf((oc0[r] + oc1[r] + po[r]) * li[r]);
        }
        // no trailing barrier: next head uses S[par^1]/rs[par^1]; Oex reuse is
        // protected by next head's barrier A (combine precedes it program-order).
    }

    // write head-averaged attention weights: thread owns (qo, kc*4 + i*128 +j)
    float* awp = aw_out + ((size_t)(b * CS) + q0 + qo) * CS + kc * 4;
#pragma unroll
    for (int i = 0; i < 8; i++)
        *(float4*)(awp + i * 128) =
            make_float4(aw[i * 4], aw[i * 4 + 1], aw[i * 4 + 2], aw[i * 4 + 3]);
}

// ---------------------------------------------------------------------------
extern "C" void kernel_launch(void* const* d_in, const int* in_sizes, int n_in,
                              void* d_out, int out_size, void* d_ws, size_t ws_size,
                              hipStream_t stream)
{
    const float* x    = (const float*)d_in[0];
    const int*   ids  = (const int*)d_in[1];
    const float* emb  = (const float*)d_in[2];
    const float* inw  = (const float*)d_in[3];
    const float* inb  = (const float*)d_in[4];
    const float* ow   = (const float*)d_in[5];
    const float* ob   = (const float*)d_in[6];
    const float* g1   = (const float*)d_in[7];
    const float* be1  = (const float*)d_in[8];
    const float* g2   = (const float*)d_in[9];
    const float* be2  = (const float*)d_in[10];
    const float* w1   = (const float*)d_in[11];
    const float* b1   = (const float*)d_in[12];
    const float* w2   = (const float*)d_in[13];
    const float* b2   = (const float*)d_in[14];

    float* out_x  = (float*)d_out;
    float* out_aw = out_x + (size_t)CB * CS * CD;

    char* p = (char*)d_ws;
    float* xr   = (float*)p; p += (size_t)NROW * CD * 4;
    float* x2   = (float*)p; p += (size_t)NROW * CD * 4;
    u16* xnb    = (u16*)p;   p += (size_t)NROW * CD * 2;
    u16* qkvb   = (u16*)p;   p += (size_t)NROW * 3 * CD * 2;
    u16* ctxb   = (u16*)p;   p += (size_t)NROW * CD * 2;
    u16* hidb   = (u16*)p;   p += (size_t)NROW * CDFF * 2;
    u16* inwb   = (u16*)p;   p += (size_t)3 * CD * CD * 2;
    u16* owb    = (u16*)p;   p += (size_t)CD * CD * 2;
    u16* w1b    = (u16*)p;   p += (size_t)CDFF * CD * 2;
    u16* w2b    = (u16*)p;   p += (size_t)CD * CDFF * 2;

    // packed Q/K/V alias the hidb region (hidb only becomes live at step 6,
    // after attention has consumed qp/kp/vp): 3 x 8.4MB <= 33.6MB
    constexpr size_t PKELEM = (size_t)CB * CH * CS * CHD;  // 4.19M u16
    u16* qp = hidb;
    u16* kp = hidb + PKELEM;
    u16* vp = hidb + 2 * PKELEM;

    dim3 blk(256);
    // 0) weight conversions
    conv_kernel<<<(3 * CD * CD) / 2048, blk, 0, stream>>>(inw, inwb);
    conv_kernel<<<(CD * CD) / 2048, blk, 0, stream>>>(ow, owb);
    conv_kernel<<<(CDFF * CD) / 2048, blk, 0, stream>>>(w1, w1b);
    conv_kernel<<<(CD * CDFF) / 2048, blk, 0, stream>>>(w2, w2b);
    // 1) x+emb, LN1 -> xr fp32, xnb bf16
    ln_kernel<<<NROW, blk, 0, stream>>>(x, ids, emb, g1, be1, xr, xnb);
    // 2) qkv projection (bf16 MFMA, bf16 out)
    gemm_mfma<0, 0, 1><<<dim3(NROW / 128, (3 * CD) / 128), blk, 0, stream>>>(
        xnb, inwb, inb, nullptr, qkvb, NROW, 3 * CD, CD);
    // 3a) Q/K/V repack into attention-coalesced layouts
    kpack_kernel<<<(int)(PKELEM / 2048), blk, 0, stream>>>(qkvb, qp, 0);
    kpack_kernel<<<(int)(PKELEM / 2048), blk, 0, stream>>>(qkvb, kp, CD);
    vpack_kernel<<<dim3(CB * (CS / 64), CH), blk, 0, stream>>>(qkvb, vp);
    // 3b) attention -> ctx bf16 + averaged weights (512 threads, 8 waves)
    attn_mfma_kernel<<<CB * (CS / 16), dim3(512), 0, stream>>>(
        qp, kp, vp, ctxb, out_aw);
    // 4) out projection + residual -> x2 fp32 (64x128 tiles: 512 blocks)
    gemm_mfma64<0, 1, 0><<<dim3(NROW / 64, CD / 128), blk, 0, stream>>>(
        ctxb, owb, ob, xr, x2, NROW, CD, CD);
    // 5) LN2 -> xnb bf16
    ln_kernel<<<NROW, blk, 0, stream>>>(x2, nullptr, nullptr, g2, be2, nullptr, xnb);
    // 6) FFN up + exact GELU -> hidb bf16
    gemm_mfma<1, 0, 1><<<dim3(NROW / 128, CDFF / 128), blk, 0, stream>>>(
        xnb, w1b, b1, nullptr, hidb, NROW, CDFF, CD);
    // 7) FFN down + bias + residual -> output fp32 (64x128 tiles: 512 blocks)
    gemm_mfma64<0, 1, 0><<<dim3(NROW / 64, CD / 128), blk, 0, stream>>>(
        hidb, w2b, b2, x2, out_x, NROW, CD, CDFF);
}